// Round 8
// baseline (285.505 us; speedup 1.0000x reference)
//
#include <hip/hip_runtime.h>
#include <hip/hip_bf16.h>
#include <stdint.h>

#define NTOK 8192
#define CD 768
#define HD 3072
#define NE 4
#define NRT 68             // 128-row tiles: sum_e ceil(n_e/128) <= 64+4
#define GCAP (NRT * 128)   // 8704 grouped (padded) rows
#define CVB 512            // wproj-cvt blocks inside fused kernel
#define G1B (NRT * (HD / 128))   // 1632 gemm1 blocks
#define G2B (NRT * (CD / 128))   // 408 gemm2 blocks

typedef __attribute__((ext_vector_type(8))) __bf16 bf16x8;
typedef __attribute__((ext_vector_type(4))) float f32x4;

__device__ __forceinline__ void gl_lds16(const void* g, void* l) {
    __builtin_amdgcn_global_load_lds(
        (const __attribute__((address_space(1))) uint32_t*)g,
        (__attribute__((address_space(3))) uint32_t*)l, 16, 0, 0);
}

__device__ __forceinline__ unsigned bf16bits(float v) {
    __hip_bfloat16 h = __float2bfloat16(v);
    return (unsigned)*reinterpret_cast<unsigned short*>(&h);
}

__device__ __forceinline__ void cvt8(const float* __restrict__ in, __hip_bfloat16* __restrict__ out, int i) {
    float4 a = *(const float4*)(in + i);
    float4 b = *(const float4*)(in + i + 4);
    union { __hip_bfloat16 h[8]; uint4 u; } pk;
    pk.h[0] = __float2bfloat16(a.x); pk.h[1] = __float2bfloat16(a.y);
    pk.h[2] = __float2bfloat16(a.z); pk.h[3] = __float2bfloat16(a.w);
    pk.h[4] = __float2bfloat16(b.x); pk.h[5] = __float2bfloat16(b.y);
    pk.h[6] = __float2bfloat16(b.z); pk.h[7] = __float2bfloat16(b.w);
    *(uint4*)(out + i) = pk.u;
}

// -------- fused front: blocks 0..255 = router(+x cvt); blocks 256+ = wfc cvt --------
__global__ __launch_bounds__(256) void k_front(
        const float* __restrict__ x, const float* __restrict__ wr,
        const float* __restrict__ wfc,
        __hip_bfloat16* __restrict__ xb, __hip_bfloat16* __restrict__ wfcb,
        int* __restrict__ eidx, float* __restrict__ pred) {
    if (blockIdx.x >= 256) {
        const int NW = NE * HD * CD;
        const int stride = (gridDim.x - 256) * 256 * 8;
        int i0 = ((blockIdx.x - 256) * 256 + threadIdx.x) * 8;
        for (int i = i0; i < NW; i += stride) cvt8(wfc, wfcb, i);
        return;
    }
    int lane = threadIdx.x & 63;
    int wave = threadIdx.x >> 6;
    float4 wv[NE][3];
    #pragma unroll
    for (int e = 0; e < NE; ++e)
        #pragma unroll
        for (int j = 0; j < 3; ++j)
            wv[e][j] = *(const float4*)(wr + e * CD + j * 256 + lane * 4);
    float sp0 = 0.f, sp1 = 0.f, sp2 = 0.f, sp3 = 0.f, zs = 0.f, hs = 0.f;
    int c0 = 0, c1 = 0, c2 = 0, c3 = 0;
    int t0 = blockIdx.x * 32 + wave * 8;
    for (int it = 0; it < 8; ++it) {
        int t = t0 + it;
        const float* xr = x + (size_t)t * CD;
        float a0 = 0.f, a1 = 0.f, a2 = 0.f, a3 = 0.f;
        #pragma unroll
        for (int j = 0; j < 3; ++j) {
            float4 xv = *(const float4*)(xr + j * 256 + lane * 4);
            a0 += xv.x * wv[0][j].x + xv.y * wv[0][j].y + xv.z * wv[0][j].z + xv.w * wv[0][j].w;
            a1 += xv.x * wv[1][j].x + xv.y * wv[1][j].y + xv.z * wv[1][j].z + xv.w * wv[1][j].w;
            a2 += xv.x * wv[2][j].x + xv.y * wv[2][j].y + xv.z * wv[2][j].z + xv.w * wv[2][j].w;
            a3 += xv.x * wv[3][j].x + xv.y * wv[3][j].y + xv.z * wv[3][j].z + xv.w * wv[3][j].w;
        }
        #pragma unroll
        for (int off = 32; off; off >>= 1) {
            a0 += __shfl_xor(a0, off); a1 += __shfl_xor(a1, off);
            a2 += __shfl_xor(a2, off); a3 += __shfl_xor(a3, off);
        }
        if (lane == 0) {
            float l[NE] = {a0, a1, a2, a3};
            int best = 0; float m = l[0];
            #pragma unroll
            for (int e = 1; e < NE; ++e) if (l[e] > m) { m = l[e]; best = e; }
            float p[NE], s = 0.f;
            #pragma unroll
            for (int e = 0; e < NE; ++e) { p[e] = expf(l[e] - m); s += p[e]; }
            float inv = 1.f / s, ent = 0.f;
            #pragma unroll
            for (int e = 0; e < NE; ++e) {
                p[e] *= inv;
                ent -= p[e] * logf(p[e] + 1e-9f);
            }
            sp0 += p[0]; sp1 += p[1]; sp2 += p[2]; sp3 += p[3];
            float lse = m + logf(s);
            zs += lse * lse; hs += ent;
            if (best == 0) c0++; else if (best == 1) c1++; else if (best == 2) c2++; else c3++;
            eidx[t] = best;
        }
    }
    __shared__ float red[4][10];
    if (lane == 0) {
        red[wave][0] = sp0; red[wave][1] = sp1; red[wave][2] = sp2; red[wave][3] = sp3;
        red[wave][4] = zs;  red[wave][5] = hs;
        red[wave][6] = (float)c0; red[wave][7] = (float)c1;
        red[wave][8] = (float)c2; red[wave][9] = (float)c3;
    }
    __syncthreads();
    if (threadIdx.x < 10)
        pred[blockIdx.x * 10 + threadIdx.x] =
            red[0][threadIdx.x] + red[1][threadIdx.x] + red[2][threadIdx.x] + red[3][threadIdx.x];
    const float* xsrc = x + (size_t)blockIdx.x * 32 * CD;
    __hip_bfloat16* xdst = xb + (size_t)blockIdx.x * 32 * CD;
    #pragma unroll
    for (int c = 0; c < 12; ++c) cvt8(xsrc, xdst, (c * 256 + threadIdx.x) * 8);
}

// -------- reduce partials, build tile map, scalar outputs, init tlist + done --------
__global__ __launch_bounds__(256) void k_scan(
        const float* __restrict__ pred, int* counts, int* fill, int* tilee,
        int* tlist, int* done, float* out) {
    __shared__ float sm[10];
    if (threadIdx.x < 10) {
        float s = 0.f;
        for (int i = 0; i < 256; ++i) s += pred[i * 10 + threadIdx.x];
        sm[threadIdx.x] = s;
    }
    for (int i = threadIdx.x; i < GCAP; i += 256) tlist[i] = -1;
    for (int i = threadIdx.x; i < NRT + 2; i += 256) done[i] = 0;
    __syncthreads();
    if (threadIdx.x == 0) {
        int cnt[NE];
        #pragma unroll
        for (int e = 0; e < NE; ++e) cnt[e] = (int)(sm[6 + e] + 0.5f);
        int base = 0, nt = 0;
        for (int e = 0; e < NE; ++e) {
            counts[e] = cnt[e];
            fill[e] = base;
            int tiles = (cnt[e] + 127) >> 7;
            for (int i = 0; i < tiles; ++i) tilee[nt++] = e;
            base += tiles << 7;
        }
        for (int i = nt; i < NRT; ++i) tilee[i] = -1;
        float aux = 0.f;
        for (int e = 0; e < NE; ++e)
            aux += (cnt[e] / (float)NTOK) * (sm[e] / (float)NTOK);
        out[0] = NE * aux;
        out[1] = sm[4] / (float)NTOK;
        out[2] = (sm[5] / (float)NTOK) / logf((float)NE);
        for (int e = 0; e < NE; ++e) out[3 + e] = cnt[e] / (float)NTOK;
    }
}

// wave-aggregated scatter
__global__ __launch_bounds__(256) void k_scatter(const int* __restrict__ eidx,
                                                 int* __restrict__ fill,
                                                 int* __restrict__ tlist) {
    int t = blockIdx.x * 256 + threadIdx.x;
    int e = eidx[t];
    int lane = threadIdx.x & 63;
    unsigned long long below = (1ull << lane) - 1ull;
    int base = 0;
    #pragma unroll
    for (int ee = 0; ee < NE; ++ee) {
        unsigned long long mm = __ballot(e == ee);
        if (e == ee) {
            int leader = __ffsll((unsigned long long)mm) - 1;
            int cnt = __popcll(mm);
            int b = 0;
            if (lane == leader) b = atomicAdd(&fill[ee], cnt);
            b = __shfl(b, leader);
            base = b + __popcll(mm & below);
        }
    }
    tlist[base] = t;
}

// -------- GEMM tile body (R5 structure): 128x128, BK=64, 4 waves, dbuf vmcnt(8) --------
// MODE 1: hbuf = relu(Xg @ Wfc^T)^2 (bf16). MODE 2: y = Hg @ Wproj^T (f32 scatter)
template<int MODE>
__device__ __forceinline__ void gemm_body(
        int rt, int ct, int e,
        const __hip_bfloat16* __restrict__ A, const __hip_bfloat16* __restrict__ Bw,
        const int* __restrict__ tlist, void* __restrict__ outp, char* lds) {
    constexpr int KDIM  = (MODE == 1) ? CD : HD;
    constexpr int NBROW = (MODE == 1) ? HD : CD;
    constexpr int NKT = KDIM / 64;
    const int tid = threadIdx.x;
    const int srow = tid >> 3;                   // 0..31
    const int schunk = (tid & 7) ^ (srow & 7);   // both-sides XOR swizzle (rule #21)

    const __hip_bfloat16 *ap[4], *bp[4];
    #pragma unroll
    for (int i = 0; i < 4; ++i) {
        int r = i * 32 + srow;
        if constexpr (MODE == 1) {
            int gt = tlist[rt * 128 + r];
            if (gt < 0) gt = 0;
            ap[i] = A + (size_t)gt * KDIM + schunk * 8;
        } else {
            ap[i] = A + ((size_t)rt * 128 + r) * KDIM + schunk * 8;
        }
        bp[i] = Bw + ((size_t)e * NBROW + ct * 128 + r) * KDIM + schunk * 8;
    }

    auto stage = [&](int b, int kt) {
        char* base = lds + b * 32768 + tid * 16;
        #pragma unroll
        for (int i = 0; i < 4; ++i) {
            gl_lds16(ap[i] + kt * 64, base + i * 4096);
            gl_lds16(bp[i] + kt * 64, base + 16384 + i * 4096);
        }
    };

    const int wv = tid >> 6, lane = tid & 63;
    const int wm = wv >> 1, wn = wv & 1;         // 2x2 waves, 64x64 each
    const int lr = lane & 15, lq = lane >> 4;

    f32x4 acc[4][4];
    #pragma unroll
    for (int m = 0; m < 4; ++m)
        #pragma unroll
        for (int n = 0; n < 4; ++n) acc[m][n] = (f32x4){0.f, 0.f, 0.f, 0.f};

    stage(0, 0);
    for (int kt = 0; kt < NKT; ++kt) {
        const int cb = kt & 1;
        if (kt + 1 < NKT) {
            stage(cb ^ 1, kt + 1);
            asm volatile("s_waitcnt vmcnt(8)" ::: "memory");
        } else {
            asm volatile("s_waitcnt vmcnt(0)" ::: "memory");
        }
        __builtin_amdgcn_s_barrier();
        __builtin_amdgcn_sched_barrier(0);
        const char* lA = lds + cb * 32768;
        const char* lB = lA + 16384;
        #pragma unroll
        for (int kh = 0; kh < 2; ++kh) {
            bf16x8 af[4], bq[4];
            #pragma unroll
            for (int m = 0; m < 4; ++m) {
                int r = wm * 64 + m * 16 + lr;
                int c = (kh * 4 + lq) ^ (r & 7);
                af[m] = *(const bf16x8*)(lA + r * 128 + c * 16);
            }
            #pragma unroll
            for (int n = 0; n < 4; ++n) {
                int r = wn * 64 + n * 16 + lr;
                int c = (kh * 4 + lq) ^ (r & 7);
                bq[n] = *(const bf16x8*)(lB + r * 128 + c * 16);
            }
            #pragma unroll
            for (int m = 0; m < 4; ++m)
                #pragma unroll
                for (int n = 0; n < 4; ++n)
                    acc[m][n] = __builtin_amdgcn_mfma_f32_16x16x32_bf16(af[m], bq[n], acc[m][n], 0, 0, 0);
        }
        __builtin_amdgcn_s_barrier();
        __builtin_amdgcn_sched_barrier(0);
    }

    if constexpr (MODE == 1) {
        __hip_bfloat16* hbuf = (__hip_bfloat16*)outp;
        int colb = ct * 128 + wn * 64;
        #pragma unroll
        for (int m = 0; m < 4; ++m) {
            int row0 = rt * 128 + wm * 64 + m * 16 + lq * 4;
            #pragma unroll
            for (int n = 0; n < 4; ++n) {
                #pragma unroll
                for (int q = 0; q < 4; ++q) {
                    float v = fmaxf(acc[m][n][q], 0.f);
                    v *= v;
                    unsigned b = bf16bits(v);
                    unsigned ob = (unsigned)__shfl_xor((int)b, 1);
                    if (!(lane & 1))
                        *(unsigned*)(hbuf + (size_t)(row0 + q) * HD + colb + n * 16 + (lr & 14)) = b | (ob << 16);
                }
            }
        }
    } else {
        float* y = (float*)outp;
        #pragma unroll
        for (int m = 0; m < 4; ++m) {
            #pragma unroll
            for (int q = 0; q < 4; ++q) {
                int grow = rt * 128 + wm * 64 + m * 16 + lq * 4 + q;
                int t = tlist[grow];
                if (t >= 0) {
                    float* yp = y + (size_t)t * CD + ct * 128 + wn * 64 + lr;
                    #pragma unroll
                    for (int n = 0; n < 4; ++n) yp[n * 16] = acc[m][n][q];
                }
            }
        }
    }
}

// -------- fused GEMM1 + wpr-cvt + GEMM2 with per-row-tile spin dependency --------
// grid = [G1B gemm1][CVB wpr-cvt][G2B gemm2]; done[rt] release/acquire couples them.
__global__ __launch_bounds__(256, 2) void k_fused(
        const __hip_bfloat16* __restrict__ xb, const __hip_bfloat16* __restrict__ wfcb,
        __hip_bfloat16* __restrict__ wprb, __hip_bfloat16* __restrict__ hbuf,
        const float* __restrict__ wpr,
        const int* __restrict__ tilee, const int* __restrict__ tlist,
        float* __restrict__ y, int* __restrict__ done) {
    __shared__ __align__(16) char lds[65536];
    const int bid = (int)blockIdx.x;

    if (bid < G1B) {
        // ---- GEMM1 ----
        constexpr int NCT = HD / 128, Q = G1B / 8;
        int logical = (bid & 7) * Q + (bid >> 3);     // bijective (G1B % 8 == 0)
        int rt = logical / NCT, ct = logical % NCT;   // ct-fastest: A reuse in XCD
        int e = tilee[rt];
        if (e < 0) return;
        gemm_body<1>(rt, ct, e, xb, wfcb, tlist, hbuf, lds);
        __syncthreads();                              // all hbuf stores complete (vmcnt0)
        if (threadIdx.x == 0)
            __hip_atomic_fetch_add(&done[rt], 1, __ATOMIC_RELEASE, __HIP_MEMORY_SCOPE_AGENT);
    } else if (bid < G1B + CVB) {
        // ---- wproj -> bf16 convert (runs under gemm1 tail) ----
        const int NW = NE * HD * CD;
        const int stride = CVB * 256 * 8;
        for (int i = ((bid - G1B) * 256 + threadIdx.x) * 8; i < NW; i += stride)
            cvt8(wpr, wprb, i);
        __syncthreads();
        if (threadIdx.x == 0)
            __hip_atomic_fetch_add(&done[NRT], 1, __ATOMIC_RELEASE, __HIP_MEMORY_SCOPE_AGENT);
    } else {
        // ---- GEMM2 (spins until its hbuf rows + wprb ready) ----
        constexpr int NCT = CD / 128, Q = G2B / 8;
        int b2 = bid - G1B - CVB;
        int logical = (b2 & 7) * Q + (b2 >> 3);       // bijective (G2B % 8 == 0)
        int rt = logical / NCT, ct = logical % NCT;
        int e = tilee[rt];
        if (e < 0) return;
        if (threadIdx.x == 0) {
            while (__hip_atomic_load(&done[NRT], __ATOMIC_ACQUIRE, __HIP_MEMORY_SCOPE_AGENT) < CVB)
                __builtin_amdgcn_s_sleep(8);
            while (__hip_atomic_load(&done[rt], __ATOMIC_ACQUIRE, __HIP_MEMORY_SCOPE_AGENT) < (HD / 128))
                __builtin_amdgcn_s_sleep(8);
        }
        __syncthreads();
        gemm_body<2>(rt, ct, e, hbuf, wprb, tlist, y, lds);
    }
}

extern "C" void kernel_launch(void* const* d_in, const int* in_sizes, int n_in,
                              void* d_out, int out_size, void* d_ws, size_t ws_size,
                              hipStream_t stream) {
    const float* x   = (const float*)d_in[0];
    const float* wr  = (const float*)d_in[1];
    const float* wfc = (const float*)d_in[2];
    const float* wpr = (const float*)d_in[3];
    float* y = (float*)d_out;

    char* ws = (char*)d_ws;
    int*   eidx   = (int*)ws;                          // 8192 ints
    int*   counts = (int*)(ws + 32768);
    int*   fill   = (int*)(ws + 32800);
    int*   tilee  = (int*)(ws + 32832);                // 68 ints
    float* pred   = (float*)(ws + 33152);              // 256*10 floats
    int*   tlist  = (int*)(ws + 43520);                // 8704 ints -> ends 78336
    int*   done   = (int*)(ws + 78336);                // 70 ints  -> ends 78616
    __hip_bfloat16* xb   = (__hip_bfloat16*)(ws + 78848);                 // 12.6 MB
    __hip_bfloat16* wfcb = (__hip_bfloat16*)(ws + 78848 + 12582912);      // 18.9 MB
    __hip_bfloat16* wprb = (__hip_bfloat16*)(ws + 78848 + 12582912 + 18874368);
    __hip_bfloat16* hbuf = (__hip_bfloat16*)(ws + 78848 + 12582912 + 2 * 18874368);
    // total ws use ~104 MB

    k_front<<<256 + 1024, 256, 0, stream>>>(x, wr, wfc, xb, wfcb, eidx, pred);
    k_scan<<<1, 256, 0, stream>>>(pred, counts, fill, tilee, tlist, done,
                                  y + (size_t)NTOK * CD);
    k_scatter<<<NTOK / 256, 256, 0, stream>>>(eidx, fill, tlist);
    k_fused<<<G1B + CVB + G2B, 256, 0, stream>>>(xb, wfcb, wprb, hbuf, wpr,
                                                 tilee, tlist, y, done);
}

// Round 9
// 151.910 us; speedup vs baseline: 1.8794x; 1.8794x over previous
//
#include <hip/hip_runtime.h>
#include <hip/hip_bf16.h>
#include <stdint.h>

#define NTOK 8192
#define CD 768
#define HD 3072
#define NE 4
#define NRT 68             // 128-row tiles: sum_e ceil(n_e/128) <= 64+4
#define GCAP (NRT * 128)   // 8704 grouped (padded) rows
#define G1WG (NRT * (HD / 128))   // 1632 gemm1 tile blocks
#define G2WG (NRT * (CD / 128))   // 408 gemm2 tile blocks

typedef __attribute__((ext_vector_type(8))) __bf16 bf16x8;
typedef __attribute__((ext_vector_type(4))) float f32x4;

__device__ __forceinline__ void gl_lds16(const void* g, void* l) {
    __builtin_amdgcn_global_load_lds(
        (const __attribute__((address_space(1))) uint32_t*)g,
        (__attribute__((address_space(3))) uint32_t*)l, 16, 0, 0);
}

__device__ __forceinline__ unsigned bf16bits(float v) {
    __hip_bfloat16 h = __float2bfloat16(v);
    return (unsigned)*reinterpret_cast<unsigned short*>(&h);
}

__device__ __forceinline__ void cvt8(const float* __restrict__ in, __hip_bfloat16* __restrict__ out, int i) {
    float4 a = *(const float4*)(in + i);
    float4 b = *(const float4*)(in + i + 4);
    union { __hip_bfloat16 h[8]; uint4 u; } pk;
    pk.h[0] = __float2bfloat16(a.x); pk.h[1] = __float2bfloat16(a.y);
    pk.h[2] = __float2bfloat16(a.z); pk.h[3] = __float2bfloat16(a.w);
    pk.h[4] = __float2bfloat16(b.x); pk.h[5] = __float2bfloat16(b.y);
    pk.h[6] = __float2bfloat16(b.z); pk.h[7] = __float2bfloat16(b.w);
    *(uint4*)(out + i) = pk.u;
}

// -------- fused front: blocks 0..255 = router(+x cvt); blocks 256+ = wfc cvt + tlist init --------
__global__ __launch_bounds__(256) void k_front(
        const float* __restrict__ x, const float* __restrict__ wr,
        const float* __restrict__ wfc,
        __hip_bfloat16* __restrict__ xb, __hip_bfloat16* __restrict__ wfcb,
        int* __restrict__ eidx, float* __restrict__ pred, int* __restrict__ tlist) {
    if (blockIdx.x >= 256) {
        int ti = (blockIdx.x - 256) * 256 + threadIdx.x;
        if (ti < GCAP) tlist[ti] = -1;
        const int NW = NE * HD * CD;
        const int stride = (gridDim.x - 256) * 256 * 8;
        int i0 = ((blockIdx.x - 256) * 256 + threadIdx.x) * 8;
        for (int i = i0; i < NW; i += stride) cvt8(wfc, wfcb, i);
        return;
    }
    int lane = threadIdx.x & 63;
    int wave = threadIdx.x >> 6;
    float4 wv[NE][3];
    #pragma unroll
    for (int e = 0; e < NE; ++e)
        #pragma unroll
        for (int j = 0; j < 3; ++j)
            wv[e][j] = *(const float4*)(wr + e * CD + j * 256 + lane * 4);
    float sp0 = 0.f, sp1 = 0.f, sp2 = 0.f, sp3 = 0.f, zs = 0.f, hs = 0.f;
    int c0 = 0, c1 = 0, c2 = 0, c3 = 0;
    int t0 = blockIdx.x * 32 + wave * 8;
    for (int it = 0; it < 8; ++it) {
        int t = t0 + it;
        const float* xr = x + (size_t)t * CD;
        float a0 = 0.f, a1 = 0.f, a2 = 0.f, a3 = 0.f;
        #pragma unroll
        for (int j = 0; j < 3; ++j) {
            float4 xv = *(const float4*)(xr + j * 256 + lane * 4);
            a0 += xv.x * wv[0][j].x + xv.y * wv[0][j].y + xv.z * wv[0][j].z + xv.w * wv[0][j].w;
            a1 += xv.x * wv[1][j].x + xv.y * wv[1][j].y + xv.z * wv[1][j].z + xv.w * wv[1][j].w;
            a2 += xv.x * wv[2][j].x + xv.y * wv[2][j].y + xv.z * wv[2][j].z + xv.w * wv[2][j].w;
            a3 += xv.x * wv[3][j].x + xv.y * wv[3][j].y + xv.z * wv[3][j].z + xv.w * wv[3][j].w;
        }
        #pragma unroll
        for (int off = 32; off; off >>= 1) {
            a0 += __shfl_xor(a0, off); a1 += __shfl_xor(a1, off);
            a2 += __shfl_xor(a2, off); a3 += __shfl_xor(a3, off);
        }
        if (lane == 0) {
            float l[NE] = {a0, a1, a2, a3};
            int best = 0; float m = l[0];
            #pragma unroll
            for (int e = 1; e < NE; ++e) if (l[e] > m) { m = l[e]; best = e; }
            float p[NE], s = 0.f;
            #pragma unroll
            for (int e = 0; e < NE; ++e) { p[e] = expf(l[e] - m); s += p[e]; }
            float inv = 1.f / s, ent = 0.f;
            #pragma unroll
            for (int e = 0; e < NE; ++e) {
                p[e] *= inv;
                ent -= p[e] * logf(p[e] + 1e-9f);
            }
            sp0 += p[0]; sp1 += p[1]; sp2 += p[2]; sp3 += p[3];
            float lse = m + logf(s);
            zs += lse * lse; hs += ent;
            if (best == 0) c0++; else if (best == 1) c1++; else if (best == 2) c2++; else c3++;
            eidx[t] = best;
        }
    }
    __shared__ float red[4][10];
    if (lane == 0) {
        red[wave][0] = sp0; red[wave][1] = sp1; red[wave][2] = sp2; red[wave][3] = sp3;
        red[wave][4] = zs;  red[wave][5] = hs;
        red[wave][6] = (float)c0; red[wave][7] = (float)c1;
        red[wave][8] = (float)c2; red[wave][9] = (float)c3;
    }
    __syncthreads();
    if (threadIdx.x < 10)
        pred[blockIdx.x * 10 + threadIdx.x] =
            red[0][threadIdx.x] + red[1][threadIdx.x] + red[2][threadIdx.x] + red[3][threadIdx.x];
    const float* xsrc = x + (size_t)blockIdx.x * 32 * CD;
    __hip_bfloat16* xdst = xb + (size_t)blockIdx.x * 32 * CD;
    #pragma unroll
    for (int c = 0; c < 12; ++c) cvt8(xsrc, xdst, (c * 256 + threadIdx.x) * 8);
}

// -------- deterministic atomic-free scatter; block 0 writes tilee + scalar outputs --------
__global__ __launch_bounds__(256) void k_scatter(
        const int* __restrict__ eidx, const float* __restrict__ pred,
        int* __restrict__ tilee, int* __restrict__ tlist, float* __restrict__ out) {
    const int b = blockIdx.x, tid = threadIdx.x;
    const int lane = tid & 63, wave = tid >> 6;

    // per-router-block expert counts (router block rb == tid, 256 of them)
    float a0 = pred[tid * 10 + 6], a1 = pred[tid * 10 + 7];
    float a2 = pred[tid * 10 + 8], a3 = pred[tid * 10 + 9];
    bool inp = tid < b * 8;                          // router blocks before this scatter block
    float p0 = inp ? a0 : 0.f, p1 = inp ? a1 : 0.f, p2 = inp ? a2 : 0.f, p3 = inp ? a3 : 0.f;
    #pragma unroll
    for (int off = 32; off; off >>= 1) {
        a0 += __shfl_xor(a0, off); a1 += __shfl_xor(a1, off);
        a2 += __shfl_xor(a2, off); a3 += __shfl_xor(a3, off);
        p0 += __shfl_xor(p0, off); p1 += __shfl_xor(p1, off);
        p2 += __shfl_xor(p2, off); p3 += __shfl_xor(p3, off);
    }
    __shared__ float redA[4][4], redP[4][4], redS[4][6];
    __shared__ int wcnt[4][4], base_s[4], pfx_s[4], woff_s[4][4];
    if (lane == 0) {
        redA[wave][0] = a0; redA[wave][1] = a1; redA[wave][2] = a2; redA[wave][3] = a3;
        redP[wave][0] = p0; redP[wave][1] = p1; redP[wave][2] = p2; redP[wave][3] = p3;
    }
    // this block's tokens: wave-local ranks + per-wave expert counts
    int t = b * 256 + tid;
    int e = eidx[t];
    unsigned long long below = (1ull << lane) - 1ull;
    int lrank = 0, mycnt[4];
    #pragma unroll
    for (int ee = 0; ee < NE; ++ee) {
        unsigned long long mm = __ballot(e == ee);
        if (e == ee) lrank = __popcll(mm & below);
        mycnt[ee] = __popcll(mm);
    }
    if (lane == 0) {
        #pragma unroll
        for (int ee = 0; ee < NE; ++ee) wcnt[wave][ee] = mycnt[ee];
    }
    if (b == 0) {                                    // stat column sums for scalar outputs
        float s[6];
        #pragma unroll
        for (int c = 0; c < 6; ++c) s[c] = pred[tid * 10 + c];
        #pragma unroll
        for (int off = 32; off; off >>= 1)
            #pragma unroll
            for (int c = 0; c < 6; ++c) s[c] += __shfl_xor(s[c], off);
        if (lane == 0)
            #pragma unroll
            for (int c = 0; c < 6; ++c) redS[wave][c] = s[c];
    }
    __syncthreads();
    if (tid == 0) {
        int cnt[NE], bb = 0, nt = 0;
        #pragma unroll
        for (int ee = 0; ee < NE; ++ee) {
            cnt[ee] = (int)(redA[0][ee] + redA[1][ee] + redA[2][ee] + redA[3][ee] + 0.5f);
            base_s[ee] = bb;
            bb += ((cnt[ee] + 127) >> 7) << 7;
        }
        if (b == 0) {
            for (int ee = 0; ee < NE; ++ee) {
                int tiles = (cnt[ee] + 127) >> 7;
                for (int i = 0; i < tiles; ++i) tilee[nt++] = ee;
            }
            for (int i = nt; i < NRT; ++i) tilee[i] = -1;
            float sm[6];
            #pragma unroll
            for (int c = 0; c < 6; ++c)
                sm[c] = redS[0][c] + redS[1][c] + redS[2][c] + redS[3][c];
            float aux = 0.f;
            for (int ee = 0; ee < NE; ++ee)
                aux += (cnt[ee] / (float)NTOK) * (sm[ee] / (float)NTOK);
            out[0] = NE * aux;
            out[1] = sm[4] / (float)NTOK;
            out[2] = (sm[5] / (float)NTOK) / logf((float)NE);
            for (int ee = 0; ee < NE; ++ee) out[3 + ee] = cnt[ee] / (float)NTOK;
        }
    }
    if (tid == 1) {
        #pragma unroll
        for (int ee = 0; ee < NE; ++ee)
            pfx_s[ee] = (int)(redP[0][ee] + redP[1][ee] + redP[2][ee] + redP[3][ee] + 0.5f);
    }
    if (tid == 2) {
        #pragma unroll
        for (int ee = 0; ee < NE; ++ee) {
            int s = 0;
            for (int w = 0; w < 4; ++w) { woff_s[w][ee] = s; s += wcnt[w][ee]; }
        }
    }
    __syncthreads();
    tlist[base_s[e] + pfx_s[e] + woff_s[wave][e] + lrank] = t;
}

// -------- GEMM tile body (R5 structure): 128x128, BK=64, 4 waves, dbuf vmcnt(8) --------
template<int MODE>
__device__ __forceinline__ void gemm_body(
        int rt, int ct, int e,
        const __hip_bfloat16* __restrict__ A, const __hip_bfloat16* __restrict__ Bw,
        const int* __restrict__ tlist, void* __restrict__ outp, char* lds) {
    constexpr int KDIM  = (MODE == 1) ? CD : HD;
    constexpr int NBROW = (MODE == 1) ? HD : CD;
    constexpr int NKT = KDIM / 64;
    const int tid = threadIdx.x;
    const int srow = tid >> 3;
    const int schunk = (tid & 7) ^ (srow & 7);   // both-sides XOR swizzle (rule #21)

    const __hip_bfloat16 *ap[4], *bp[4];
    #pragma unroll
    for (int i = 0; i < 4; ++i) {
        int r = i * 32 + srow;
        if constexpr (MODE == 1) {
            int gt = tlist[rt * 128 + r];
            if (gt < 0) gt = 0;
            ap[i] = A + (size_t)gt * KDIM + schunk * 8;
        } else {
            ap[i] = A + ((size_t)rt * 128 + r) * KDIM + schunk * 8;
        }
        bp[i] = Bw + ((size_t)e * NBROW + ct * 128 + r) * KDIM + schunk * 8;
    }

    auto stage = [&](int bsl, int kt) {
        char* base = lds + bsl * 32768 + tid * 16;
        #pragma unroll
        for (int i = 0; i < 4; ++i) {
            gl_lds16(ap[i] + kt * 64, base + i * 4096);
            gl_lds16(bp[i] + kt * 64, base + 16384 + i * 4096);
        }
    };

    const int wv = tid >> 6, lane = tid & 63;
    const int wm = wv >> 1, wn = wv & 1;
    const int lr = lane & 15, lq = lane >> 4;

    f32x4 acc[4][4];
    #pragma unroll
    for (int m = 0; m < 4; ++m)
        #pragma unroll
        for (int n = 0; n < 4; ++n) acc[m][n] = (f32x4){0.f, 0.f, 0.f, 0.f};

    stage(0, 0);
    for (int kt = 0; kt < NKT; ++kt) {
        const int cb = kt & 1;
        if (kt + 1 < NKT) {
            stage(cb ^ 1, kt + 1);
            asm volatile("s_waitcnt vmcnt(8)" ::: "memory");
        } else {
            asm volatile("s_waitcnt vmcnt(0)" ::: "memory");
        }
        __builtin_amdgcn_s_barrier();
        __builtin_amdgcn_sched_barrier(0);
        const char* lA = lds + cb * 32768;
        const char* lB = lA + 16384;
        #pragma unroll
        for (int kh = 0; kh < 2; ++kh) {
            bf16x8 af[4], bq[4];
            #pragma unroll
            for (int m = 0; m < 4; ++m) {
                int r = wm * 64 + m * 16 + lr;
                int c = (kh * 4 + lq) ^ (r & 7);
                af[m] = *(const bf16x8*)(lA + r * 128 + c * 16);
            }
            #pragma unroll
            for (int n = 0; n < 4; ++n) {
                int r = wn * 64 + n * 16 + lr;
                int c = (kh * 4 + lq) ^ (r & 7);
                bq[n] = *(const bf16x8*)(lB + r * 128 + c * 16);
            }
            #pragma unroll
            for (int m = 0; m < 4; ++m)
                #pragma unroll
                for (int n = 0; n < 4; ++n)
                    acc[m][n] = __builtin_amdgcn_mfma_f32_16x16x32_bf16(af[m], bq[n], acc[m][n], 0, 0, 0);
        }
        __builtin_amdgcn_s_barrier();
        __builtin_amdgcn_sched_barrier(0);
    }

    if constexpr (MODE == 1) {
        __hip_bfloat16* hbuf = (__hip_bfloat16*)outp;
        int colb = ct * 128 + wn * 64;
        #pragma unroll
        for (int m = 0; m < 4; ++m) {
            int row0 = rt * 128 + wm * 64 + m * 16 + lq * 4;
            #pragma unroll
            for (int n = 0; n < 4; ++n) {
                #pragma unroll
                for (int q = 0; q < 4; ++q) {
                    float v = fmaxf(acc[m][n][q], 0.f);
                    v *= v;
                    unsigned bb = bf16bits(v);
                    unsigned ob = (unsigned)__shfl_xor((int)bb, 1);
                    if (!(lane & 1))
                        *(unsigned*)(hbuf + (size_t)(row0 + q) * HD + colb + n * 16 + (lr & 14)) = bb | (ob << 16);
                }
            }
        }
    } else {
        float* y = (float*)outp;
        #pragma unroll
        for (int m = 0; m < 4; ++m) {
            #pragma unroll
            for (int q = 0; q < 4; ++q) {
                int grow = rt * 128 + wm * 64 + m * 16 + lq * 4 + q;
                int t = tlist[grow];
                if (t >= 0) {
                    float* yp = y + (size_t)t * CD + ct * 128 + wn * 64 + lr;
                    #pragma unroll
                    for (int n = 0; n < 4; ++n) yp[n * 16] = acc[m][n][q];
                }
            }
        }
    }
}

// -------- GEMM1 with wpr-cvt blocks interleaved in groups-of-8 (XCD-even) --------
__global__ __launch_bounds__(256, 2) void k_gemm1(
        const __hip_bfloat16* __restrict__ A, const __hip_bfloat16* __restrict__ Bw,
        const int* __restrict__ tilee, const int* __restrict__ tlist,
        __hip_bfloat16* __restrict__ hbuf,
        const float* __restrict__ wpr, __hip_bfloat16* __restrict__ wprb) {
    __shared__ __align__(16) char lds[65536];
    int bid = (int)blockIdx.x;
    int g;
    if (bid < 2048) {
        int grp = bid >> 3;
        if ((grp & 3) == 3) {            // cvt group: slots span all 8 XCDs evenly
            const int NW = NE * HD * CD;
            const int cvid = (grp >> 2) * 8 + (bid & 7);   // 0..511
            const int stride = 512 * 256 * 8;
            for (int i = (cvid * 256 + threadIdx.x) * 8; i < NW; i += stride)
                cvt8(wpr, wprb, i);
            return;
        }
        g = ((grp >> 2) * 3 + (grp & 3)) * 8 + (bid & 7);  // 0..1535
    } else {
        g = 1536 + (bid - 2048);                            // 1536..1631
    }
    // bijective XCD-chunked swizzle (g&7 == bid&7 preserved above)
    constexpr int Q = G1WG / 8;          // 204
    int logical = (g & 7) * Q + (g >> 3);
    constexpr int NCT = HD / 128;
    int rt = logical / NCT, ct = logical % NCT;
    int e = tilee[rt];
    if (e < 0) return;
    gemm_body<1>(rt, ct, e, A, Bw, tlist, hbuf, lds);
}

__global__ __launch_bounds__(256, 2) void k_gemm2(
        const __hip_bfloat16* __restrict__ A, const __hip_bfloat16* __restrict__ Bw,
        const int* __restrict__ tilee, const int* __restrict__ tlist,
        float* __restrict__ y) {
    __shared__ __align__(16) char lds[65536];
    constexpr int Q = G2WG / 8;          // 51
    int bid = (int)blockIdx.x;
    int logical = (bid & 7) * Q + (bid >> 3);
    constexpr int NCT = CD / 128;
    int rt = logical / NCT, ct = logical % NCT;
    int e = tilee[rt];
    if (e < 0) return;
    gemm_body<2>(rt, ct, e, A, Bw, tlist, y, lds);
}

extern "C" void kernel_launch(void* const* d_in, const int* in_sizes, int n_in,
                              void* d_out, int out_size, void* d_ws, size_t ws_size,
                              hipStream_t stream) {
    const float* x   = (const float*)d_in[0];
    const float* wr  = (const float*)d_in[1];
    const float* wfc = (const float*)d_in[2];
    const float* wpr = (const float*)d_in[3];
    float* y = (float*)d_out;

    char* ws = (char*)d_ws;
    int*   eidx   = (int*)ws;                          // 8192 ints
    int*   tilee  = (int*)(ws + 32832);                // 68 ints
    float* pred   = (float*)(ws + 33152);              // 256*10 floats
    int*   tlist  = (int*)(ws + 43520);                // 8704 ints
    __hip_bfloat16* xb   = (__hip_bfloat16*)(ws + 78848);                 // 12.6 MB
    __hip_bfloat16* wfcb = (__hip_bfloat16*)(ws + 78848 + 12582912);      // 18.9 MB
    __hip_bfloat16* wprb = (__hip_bfloat16*)(ws + 78848 + 12582912 + 18874368);
    __hip_bfloat16* hbuf = (__hip_bfloat16*)(ws + 78848 + 12582912 + 2 * 18874368);
    // total ws use ~104 MB

    k_front<<<256 + 1024, 256, 0, stream>>>(x, wr, wfc, xb, wfcb, eidx, pred, tlist);
    k_scatter<<<NTOK / 256, 256, 0, stream>>>(eidx, pred, tilee, tlist,
                                              y + (size_t)NTOK * CD);
    k_gemm1<<<2048 + 96, 256, 0, stream>>>(xb, wfcb, tilee, tlist, hbuf, wpr, wprb);
    k_gemm2<<<G2WG, 256, 0, stream>>>(hbuf, wprb, tilee, tlist, y);
}

// Round 10
// 142.561 us; speedup vs baseline: 2.0027x; 1.0656x over previous
//
#include <hip/hip_runtime.h>
#include <hip/hip_bf16.h>
#include <stdint.h>

#define NTOK 8192
#define CD 768
#define HD 3072
#define NE 4
#define NRT2 36            // 256-row group tiles (gemm1)
#define NRT1 72            // 128-row view of same grouping (gemm2)
#define GCAP (NRT2 * 256)  // 9216 grouped (padded) rows
#define G1WG (NRT2 * (HD / 256))   // 432 gemm1 blocks
#define G1CV 128                   // wpr-cvt blocks appended to gemm1
#define G2WG (NRT1 * (CD / 128))   // 432 gemm2 blocks

typedef __attribute__((ext_vector_type(8))) __bf16 bf16x8;
typedef __attribute__((ext_vector_type(4))) float f32x4;

__device__ __forceinline__ void gl_lds16(const void* g, void* l) {
    __builtin_amdgcn_global_load_lds(
        (const __attribute__((address_space(1))) uint32_t*)g,
        (__attribute__((address_space(3))) uint32_t*)l, 16, 0, 0);
}

__device__ __forceinline__ unsigned bf16bits(float v) {
    __hip_bfloat16 h = __float2bfloat16(v);
    return (unsigned)*reinterpret_cast<unsigned short*>(&h);
}

__device__ __forceinline__ void cvt8(const float* __restrict__ in, __hip_bfloat16* __restrict__ out, int i) {
    float4 a = *(const float4*)(in + i);
    float4 b = *(const float4*)(in + i + 4);
    union { __hip_bfloat16 h[8]; uint4 u; } pk;
    pk.h[0] = __float2bfloat16(a.x); pk.h[1] = __float2bfloat16(a.y);
    pk.h[2] = __float2bfloat16(a.z); pk.h[3] = __float2bfloat16(a.w);
    pk.h[4] = __float2bfloat16(b.x); pk.h[5] = __float2bfloat16(b.y);
    pk.h[6] = __float2bfloat16(b.z); pk.h[7] = __float2bfloat16(b.w);
    *(uint4*)(out + i) = pk.u;
}

// -------- fused front: blocks 0..255 = router(+x cvt); blocks 256+ = wfc cvt + tlist init --------
__global__ __launch_bounds__(256) void k_front(
        const float* __restrict__ x, const float* __restrict__ wr,
        const float* __restrict__ wfc,
        __hip_bfloat16* __restrict__ xb, __hip_bfloat16* __restrict__ wfcb,
        int* __restrict__ eidx, float* __restrict__ pred, int* __restrict__ tlist) {
    if (blockIdx.x >= 256) {
        int ti = (blockIdx.x - 256) * 256 + threadIdx.x;
        if (ti < GCAP) tlist[ti] = -1;
        const int NW = NE * HD * CD;
        const int stride = (gridDim.x - 256) * 256 * 8;
        int i0 = ((blockIdx.x - 256) * 256 + threadIdx.x) * 8;
        for (int i = i0; i < NW; i += stride) cvt8(wfc, wfcb, i);
        return;
    }
    int lane = threadIdx.x & 63;
    int wave = threadIdx.x >> 6;
    float4 wv[NE][3];
    #pragma unroll
    for (int e = 0; e < NE; ++e)
        #pragma unroll
        for (int j = 0; j < 3; ++j)
            wv[e][j] = *(const float4*)(wr + e * CD + j * 256 + lane * 4);
    float sp0 = 0.f, sp1 = 0.f, sp2 = 0.f, sp3 = 0.f, zs = 0.f, hs = 0.f;
    int c0 = 0, c1 = 0, c2 = 0, c3 = 0;
    int t0 = blockIdx.x * 32 + wave * 8;
    for (int it = 0; it < 8; ++it) {
        int t = t0 + it;
        const float* xr = x + (size_t)t * CD;
        float a0 = 0.f, a1 = 0.f, a2 = 0.f, a3 = 0.f;
        #pragma unroll
        for (int j = 0; j < 3; ++j) {
            float4 xv = *(const float4*)(xr + j * 256 + lane * 4);
            a0 += xv.x * wv[0][j].x + xv.y * wv[0][j].y + xv.z * wv[0][j].z + xv.w * wv[0][j].w;
            a1 += xv.x * wv[1][j].x + xv.y * wv[1][j].y + xv.z * wv[1][j].z + xv.w * wv[1][j].w;
            a2 += xv.x * wv[2][j].x + xv.y * wv[2][j].y + xv.z * wv[2][j].z + xv.w * wv[2][j].w;
            a3 += xv.x * wv[3][j].x + xv.y * wv[3][j].y + xv.z * wv[3][j].z + xv.w * wv[3][j].w;
        }
        #pragma unroll
        for (int off = 32; off; off >>= 1) {
            a0 += __shfl_xor(a0, off); a1 += __shfl_xor(a1, off);
            a2 += __shfl_xor(a2, off); a3 += __shfl_xor(a3, off);
        }
        if (lane == 0) {
            float l[NE] = {a0, a1, a2, a3};
            int best = 0; float m = l[0];
            #pragma unroll
            for (int e = 1; e < NE; ++e) if (l[e] > m) { m = l[e]; best = e; }
            float p[NE], s = 0.f;
            #pragma unroll
            for (int e = 0; e < NE; ++e) { p[e] = expf(l[e] - m); s += p[e]; }
            float inv = 1.f / s, ent = 0.f;
            #pragma unroll
            for (int e = 0; e < NE; ++e) {
                p[e] *= inv;
                ent -= p[e] * logf(p[e] + 1e-9f);
            }
            sp0 += p[0]; sp1 += p[1]; sp2 += p[2]; sp3 += p[3];
            float lse = m + logf(s);
            zs += lse * lse; hs += ent;
            if (best == 0) c0++; else if (best == 1) c1++; else if (best == 2) c2++; else c3++;
            eidx[t] = best;
        }
    }
    __shared__ float red[4][10];
    if (lane == 0) {
        red[wave][0] = sp0; red[wave][1] = sp1; red[wave][2] = sp2; red[wave][3] = sp3;
        red[wave][4] = zs;  red[wave][5] = hs;
        red[wave][6] = (float)c0; red[wave][7] = (float)c1;
        red[wave][8] = (float)c2; red[wave][9] = (float)c3;
    }
    __syncthreads();
    if (threadIdx.x < 10)
        pred[blockIdx.x * 10 + threadIdx.x] =
            red[0][threadIdx.x] + red[1][threadIdx.x] + red[2][threadIdx.x] + red[3][threadIdx.x];
    const float* xsrc = x + (size_t)blockIdx.x * 32 * CD;
    __hip_bfloat16* xdst = xb + (size_t)blockIdx.x * 32 * CD;
    #pragma unroll
    for (int c = 0; c < 12; ++c) cvt8(xsrc, xdst, (c * 256 + threadIdx.x) * 8);
}

// -------- deterministic atomic-free scatter (256-row padding); block 0 writes tilee + scalars --------
__global__ __launch_bounds__(256) void k_scatter(
        const int* __restrict__ eidx, const float* __restrict__ pred,
        int* __restrict__ t256, int* __restrict__ t128,
        int* __restrict__ tlist, float* __restrict__ out) {
    const int b = blockIdx.x, tid = threadIdx.x;
    const int lane = tid & 63, wave = tid >> 6;

    float a0 = pred[tid * 10 + 6], a1 = pred[tid * 10 + 7];
    float a2 = pred[tid * 10 + 8], a3 = pred[tid * 10 + 9];
    bool inp = tid < b * 8;
    float p0 = inp ? a0 : 0.f, p1 = inp ? a1 : 0.f, p2 = inp ? a2 : 0.f, p3 = inp ? a3 : 0.f;
    #pragma unroll
    for (int off = 32; off; off >>= 1) {
        a0 += __shfl_xor(a0, off); a1 += __shfl_xor(a1, off);
        a2 += __shfl_xor(a2, off); a3 += __shfl_xor(a3, off);
        p0 += __shfl_xor(p0, off); p1 += __shfl_xor(p1, off);
        p2 += __shfl_xor(p2, off); p3 += __shfl_xor(p3, off);
    }
    __shared__ float redA[4][4], redP[4][4], redS[4][6];
    __shared__ int wcnt[4][4], base_s[4], pfx_s[4], woff_s[4][4];
    if (lane == 0) {
        redA[wave][0] = a0; redA[wave][1] = a1; redA[wave][2] = a2; redA[wave][3] = a3;
        redP[wave][0] = p0; redP[wave][1] = p1; redP[wave][2] = p2; redP[wave][3] = p3;
    }
    int t = b * 256 + tid;
    int e = eidx[t];
    unsigned long long below = (1ull << lane) - 1ull;
    int lrank = 0, mycnt[4];
    #pragma unroll
    for (int ee = 0; ee < NE; ++ee) {
        unsigned long long mm = __ballot(e == ee);
        if (e == ee) lrank = __popcll(mm & below);
        mycnt[ee] = __popcll(mm);
    }
    if (lane == 0) {
        #pragma unroll
        for (int ee = 0; ee < NE; ++ee) wcnt[wave][ee] = mycnt[ee];
    }
    if (b == 0) {
        float s[6];
        #pragma unroll
        for (int c = 0; c < 6; ++c) s[c] = pred[tid * 10 + c];
        #pragma unroll
        for (int off = 32; off; off >>= 1)
            #pragma unroll
            for (int c = 0; c < 6; ++c) s[c] += __shfl_xor(s[c], off);
        if (lane == 0)
            #pragma unroll
            for (int c = 0; c < 6; ++c) redS[wave][c] = s[c];
    }
    __syncthreads();
    if (tid == 0) {
        int cnt[NE], bb = 0, nt = 0;
        #pragma unroll
        for (int ee = 0; ee < NE; ++ee) {
            cnt[ee] = (int)(redA[0][ee] + redA[1][ee] + redA[2][ee] + redA[3][ee] + 0.5f);
            base_s[ee] = bb;
            bb += ((cnt[ee] + 255) >> 8) << 8;
        }
        if (b == 0) {
            for (int ee = 0; ee < NE; ++ee) {
                int tiles = (cnt[ee] + 255) >> 8;
                for (int i = 0; i < tiles; ++i) t256[nt++] = ee;
            }
            for (int i = nt; i < NRT2; ++i) t256[i] = -1;
            for (int i = 0; i < NRT1; ++i) t128[i] = t256[i >> 1];
            float sm[6];
            #pragma unroll
            for (int c = 0; c < 6; ++c)
                sm[c] = redS[0][c] + redS[1][c] + redS[2][c] + redS[3][c];
            float aux = 0.f;
            for (int ee = 0; ee < NE; ++ee)
                aux += (cnt[ee] / (float)NTOK) * (sm[ee] / (float)NTOK);
            out[0] = NE * aux;
            out[1] = sm[4] / (float)NTOK;
            out[2] = (sm[5] / (float)NTOK) / logf((float)NE);
            for (int ee = 0; ee < NE; ++ee) out[3 + ee] = cnt[ee] / (float)NTOK;
        }
    }
    if (tid == 1) {
        #pragma unroll
        for (int ee = 0; ee < NE; ++ee)
            pfx_s[ee] = (int)(redP[0][ee] + redP[1][ee] + redP[2][ee] + redP[3][ee] + 0.5f);
    }
    if (tid == 2) {
        #pragma unroll
        for (int ee = 0; ee < NE; ++ee) {
            int s = 0;
            for (int w = 0; w < 4; ++w) { woff_s[w][ee] = s; s += wcnt[w][ee]; }
        }
    }
    __syncthreads();
    tlist[base_s[e] + pfx_s[e] + woff_s[wave][e] + lrank] = t;
}

// -------- GEMM1: 256x256 tile, BK=64, 8 waves (2Mx4N), 8-phase counted-vmcnt schedule --------
// hbuf = relu(Xg @ Wfc^T)^2 (bf16). Appended blocks convert wpr -> bf16.
__global__ __launch_bounds__(512, 2) void k_gemm1(
        const __hip_bfloat16* __restrict__ xb, const __hip_bfloat16* __restrict__ wfcb,
        const int* __restrict__ t256, const int* __restrict__ tlist,
        __hip_bfloat16* __restrict__ hbuf,
        const float* __restrict__ wpr, __hip_bfloat16* __restrict__ wprb) {
    __shared__ __align__(16) char lds[131072];   // 2 slots x {A[2kh][256r][64B], B same}
    int bid = (int)blockIdx.x;
    if (bid >= G1WG) {                           // wpr-cvt blocks (fill round-2 slack)
        const int NW = NE * HD * CD;
        const int stride = G1CV * 512 * 8;
        for (int i = ((bid - G1WG) * 512 + threadIdx.x) * 8; i < NW; i += stride)
            cvt8(wpr, wprb, i);
        return;
    }
    constexpr int Q = G1WG / 8;                  // 54, exact
    int logical = (bid & 7) * Q + (bid >> 3);
    int rt = logical / (HD / 256), ct = logical % (HD / 256);
    const int e = t256[rt];
    if (e < 0) return;

    const int tid = threadIdx.x;
    // ---- staging: half-tile = one K-half plane (16KB), 2 gl_lds16/thread ----
    int r0 = tid >> 2, r1 = 128 + (tid >> 2);
    int ch0 = (tid & 3) ^ ((r0 >> 1) & 3);       // pre-swizzled source chunk (rule #21)
    int ch1 = (tid & 3) ^ ((r1 >> 1) & 3);
    int gt0 = tlist[rt * 256 + r0]; if (gt0 < 0) gt0 = 0;
    int gt1 = tlist[rt * 256 + r1]; if (gt1 < 0) gt1 = 0;
    const __hip_bfloat16* as0 = xb + (size_t)gt0 * CD + ch0 * 8;
    const __hip_bfloat16* as1 = xb + (size_t)gt1 * CD + ch1 * 8;
    const __hip_bfloat16* bs0 = wfcb + ((size_t)e * HD + ct * 256 + r0) * CD + ch0 * 8;
    const __hip_bfloat16* bs1 = wfcb + ((size_t)e * HD + ct * 256 + r1) * CD + ch1 * 8;

    auto stgA = [&](int s, int kh, int kt) {
        char* d = lds + s * 65536 + kh * 16384 + tid * 16;
        gl_lds16(as0 + kt * 64 + kh * 32, d);
        gl_lds16(as1 + kt * 64 + kh * 32, d + 8192);
    };
    auto stgB = [&](int s, int kh, int kt) {
        char* d = lds + s * 65536 + 32768 + kh * 16384 + tid * 16;
        gl_lds16(bs0 + kt * 64 + kh * 32, d);
        gl_lds16(bs1 + kt * 64 + kh * 32, d + 8192);
    };

    const int wv = tid >> 6, lane = tid & 63;
    const int wm = wv >> 2, wn = wv & 3;         // 2M x 4N, per-wave 128x64
    const int lr = lane & 15, lq = lane >> 4;

    auto lda = [&](int s, int kk, int f) -> bf16x8 {
        int r = wm * 128 + f * 16 + lr;
        int off = s * 65536 + kk * 16384 + r * 64 + ((lq ^ ((r >> 1) & 3)) << 4);
        return *(const bf16x8*)(lds + off);
    };
    auto ldb = [&](int s, int kk, int g) -> bf16x8 {
        int r = wn * 64 + g * 16 + lr;
        int off = s * 65536 + 32768 + kk * 16384 + r * 64 + ((lq ^ ((r >> 1) & 3)) << 4);
        return *(const bf16x8*)(lds + off);
    };

    f32x4 acc[8][4];
    #pragma unroll
    for (int f = 0; f < 8; ++f)
        #pragma unroll
        for (int g = 0; g < 4; ++g) acc[f][g] = (f32x4){0.f, 0.f, 0.f, 0.f};

    #define MIDBAR() do { __builtin_amdgcn_s_barrier(); \
        asm volatile("s_waitcnt lgkmcnt(0)" ::: "memory"); \
        __builtin_amdgcn_sched_barrier(0); } while (0)
    #define ENDBAR() do { __builtin_amdgcn_s_barrier(); \
        __builtin_amdgcn_sched_barrier(0); } while (0)
    #define MFMA16(mb) do { __builtin_amdgcn_s_setprio(1); \
        _Pragma("unroll") \
        for (int f = 0; f < 4; ++f) \
            _Pragma("unroll") \
            for (int g = 0; g < 4; ++g) \
                acc[(mb) + f][g] = __builtin_amdgcn_mfma_f32_16x16x32_bf16(afr[f], bfr[g], acc[(mb) + f][g], 0, 0, 0); \
        __builtin_amdgcn_s_setprio(0); } while (0)

    // prologue: kt=0 -> slot0 (order fixes vmcnt ledger: Akh0,Bkh0 oldest)
    stgA(0, 0, 0); stgB(0, 0, 0); stgA(0, 1, 0); stgB(0, 1, 0);
    asm volatile("s_waitcnt vmcnt(4)" ::: "memory");   // Akh0+Bkh0 landed
    ENDBAR();

    constexpr int NKT = CD / 64;   // 12
    #pragma unroll 2
    for (int kt = 0; kt < NKT; ++kt) {
        const int s = kt & 1, ns = s ^ 1;
        const bool pf = (kt + 1 < NKT);
        bf16x8 afr[4], bfr[4];
        // ph0: (kk0, m0-3); stage kt+1 A-kh0
        #pragma unroll
        for (int g = 0; g < 4; ++g) bfr[g] = ldb(s, 0, g);
        #pragma unroll
        for (int f = 0; f < 4; ++f) afr[f] = lda(s, 0, f);
        if (pf) stgA(ns, 0, kt + 1);
        MIDBAR();
        MFMA16(0);
        ENDBAR();
        // ph1: (kk0, m4-7) B reuse; stage kt+1 B-kh0; vmcnt(4) -> kt's kh1 planes landed
        #pragma unroll
        for (int f = 0; f < 4; ++f) afr[f] = lda(s, 0, 4 + f);
        if (pf) stgB(ns, 0, kt + 1);
        MIDBAR();
        MFMA16(4);
        if (pf) asm volatile("s_waitcnt vmcnt(4)" ::: "memory");
        else    asm volatile("s_waitcnt vmcnt(0)" ::: "memory");
        ENDBAR();
        // ph2: (kk1, m4-7); stage kt+1 A-kh1
        #pragma unroll
        for (int g = 0; g < 4; ++g) bfr[g] = ldb(s, 1, g);
        #pragma unroll
        for (int f = 0; f < 4; ++f) afr[f] = lda(s, 1, 4 + f);
        if (pf) stgA(ns, 1, kt + 1);
        MIDBAR();
        MFMA16(4);
        ENDBAR();
        // ph3: (kk1, m0-3) B reuse; stage kt+1 B-kh1; vmcnt(4) -> kt+1's kh0 planes landed
        #pragma unroll
        for (int f = 0; f < 4; ++f) afr[f] = lda(s, 1, f);
        if (pf) stgB(ns, 1, kt + 1);
        MIDBAR();
        MFMA16(0);
        if (pf) asm volatile("s_waitcnt vmcnt(4)" ::: "memory");
        ENDBAR();
    }
    #undef MIDBAR
    #undef ENDBAR
    #undef MFMA16

    // epilogue: relu^2 -> bf16 packed stores
    int colb = ct * 256 + wn * 64;
    #pragma unroll
    for (int f = 0; f < 8; ++f) {
        int row0 = rt * 256 + wm * 128 + f * 16 + lq * 4;
        #pragma unroll
        for (int g = 0; g < 4; ++g) {
            #pragma unroll
            for (int q = 0; q < 4; ++q) {
                float v = fmaxf(acc[f][g][q], 0.f);
                v *= v;
                unsigned bb = bf16bits(v);
                unsigned ob = (unsigned)__shfl_xor((int)bb, 1);
                if (!(lane & 1))
                    *(unsigned*)(hbuf + (size_t)(row0 + q) * HD + colb + g * 16 + (lr & 14)) = bb | (ob << 16);
            }
        }
    }
}

// -------- GEMM2 (R8 body, unchanged): 128x128 tile, BK=64, 4 waves, dbuf vmcnt(8) --------
__global__ __launch_bounds__(256, 2) void k_gemm2(
        const __hip_bfloat16* __restrict__ hbuf, const __hip_bfloat16* __restrict__ wprb,
        const int* __restrict__ t128, const int* __restrict__ tlist,
        float* __restrict__ y) {
    __shared__ __align__(16) char lds[65536];
    constexpr int Q = G2WG / 8;          // 54
    int bid = (int)blockIdx.x;
    int logical = (bid & 7) * Q + (bid >> 3);
    constexpr int NCT = CD / 128;
    int rt = logical / NCT, ct = logical % NCT;
    const int e = t128[rt];
    if (e < 0) return;

    const int tid = threadIdx.x;
    const int srow = tid >> 3;
    const int schunk = (tid & 7) ^ (srow & 7);

    const __hip_bfloat16 *ap[4], *bp[4];
    #pragma unroll
    for (int i = 0; i < 4; ++i) {
        int r = i * 32 + srow;
        ap[i] = hbuf + ((size_t)rt * 128 + r) * HD + schunk * 8;
        bp[i] = wprb + ((size_t)e * CD + ct * 128 + r) * HD + schunk * 8;
    }

    auto stage = [&](int bsl, int kt) {
        char* base = lds + bsl * 32768 + tid * 16;
        #pragma unroll
        for (int i = 0; i < 4; ++i) {
            gl_lds16(ap[i] + kt * 64, base + i * 4096);
            gl_lds16(bp[i] + kt * 64, base + 16384 + i * 4096);
        }
    };

    const int wv = tid >> 6, lane = tid & 63;
    const int wm = wv >> 1, wn = wv & 1;
    const int lr = lane & 15, lq = lane >> 4;

    f32x4 acc[4][4];
    #pragma unroll
    for (int m = 0; m < 4; ++m)
        #pragma unroll
        for (int n = 0; n < 4; ++n) acc[m][n] = (f32x4){0.f, 0.f, 0.f, 0.f};

    constexpr int NKT = HD / 64;
    stage(0, 0);
    for (int kt = 0; kt < NKT; ++kt) {
        const int cb = kt & 1;
        if (kt + 1 < NKT) {
            stage(cb ^ 1, kt + 1);
            asm volatile("s_waitcnt vmcnt(8)" ::: "memory");
        } else {
            asm volatile("s_waitcnt vmcnt(0)" ::: "memory");
        }
        __builtin_amdgcn_s_barrier();
        __builtin_amdgcn_sched_barrier(0);
        const char* lA = lds + cb * 32768;
        const char* lB = lA + 16384;
        #pragma unroll
        for (int kh = 0; kh < 2; ++kh) {
            bf16x8 af[4], bq[4];
            #pragma unroll
            for (int m = 0; m < 4; ++m) {
                int r = wm * 64 + m * 16 + lr;
                int c = (kh * 4 + lq) ^ (r & 7);
                af[m] = *(const bf16x8*)(lA + r * 128 + c * 16);
            }
            #pragma unroll
            for (int n = 0; n < 4; ++n) {
                int r = wn * 64 + n * 16 + lr;
                int c = (kh * 4 + lq) ^ (r & 7);
                bq[n] = *(const bf16x8*)(lB + r * 128 + c * 16);
            }
            #pragma unroll
            for (int m = 0; m < 4; ++m)
                #pragma unroll
                for (int n = 0; n < 4; ++n)
                    acc[m][n] = __builtin_amdgcn_mfma_f32_16x16x32_bf16(af[m], bq[n], acc[m][n], 0, 0, 0);
        }
        __builtin_amdgcn_s_barrier();
        __builtin_amdgcn_sched_barrier(0);
    }

    #pragma unroll
    for (int m = 0; m < 4; ++m) {
        #pragma unroll
        for (int q = 0; q < 4; ++q) {
            int grow = rt * 128 + wm * 64 + m * 16 + lq * 4 + q;
            int t = tlist[grow];
            if (t >= 0) {
                float* yp = y + (size_t)t * CD + ct * 128 + wn * 64 + lr;
                #pragma unroll
                for (int n = 0; n < 4; ++n) yp[n * 16] = acc[m][n][q];
            }
        }
    }
}

extern "C" void kernel_launch(void* const* d_in, const int* in_sizes, int n_in,
                              void* d_out, int out_size, void* d_ws, size_t ws_size,
                              hipStream_t stream) {
    const float* x   = (const float*)d_in[0];
    const float* wr  = (const float*)d_in[1];
    const float* wfc = (const float*)d_in[2];
    const float* wpr = (const float*)d_in[3];
    float* y = (float*)d_out;

    char* ws = (char*)d_ws;
    int*   eidx  = (int*)ws;                           // 8192 ints
    int*   t256  = (int*)(ws + 32768);                 // 36 ints
    int*   t128  = (int*)(ws + 32960);                 // 72 ints
    float* pred  = (float*)(ws + 33280);               // 2560 floats -> 43520
    int*   tlist = (int*)(ws + 43776);                 // 9216 ints -> 80640
    __hip_bfloat16* xb   = (__hip_bfloat16*)(ws + 81152);                 // 12.6 MB
    __hip_bfloat16* wfcb = (__hip_bfloat16*)(ws + 81152 + 12582912);      // 18.9 MB
    __hip_bfloat16* wprb = (__hip_bfloat16*)(ws + 81152 + 12582912 + 18874368);
    __hip_bfloat16* hbuf = (__hip_bfloat16*)(ws + 81152 + 12582912 + 2 * 18874368);
    // hbuf 9216*3072*2 = 56.6 MB; total ws use ~107.1 MB

    k_front<<<256 + 1024, 256, 0, stream>>>(x, wr, wfc, xb, wfcb, eidx, pred, tlist);
    k_scatter<<<NTOK / 256, 256, 0, stream>>>(eidx, pred, t256, t128, tlist,
                                              y + (size_t)NTOK * CD);
    k_gemm1<<<G1WG + G1CV, 512, 0, stream>>>(xb, wfcb, t256, tlist, hbuf, wpr, wprb);
    k_gemm2<<<G2WG, 256, 0, stream>>>(hbuf, wprb, t128, tlist, y);
}

// Round 11
// 141.279 us; speedup vs baseline: 2.0209x; 1.0091x over previous
//
#include <hip/hip_runtime.h>
#include <hip/hip_bf16.h>
#include <stdint.h>

#define NTOK 8192
#define CD 768
#define HD 3072
#define NE 4
#define NRT2 36            // 256-row group tiles (gemm1)
#define NRT1 72            // 128-row view of same grouping (gemm2)
#define GCAP (NRT2 * 256)  // 9216 grouped (padded) rows
#define G1WG (NRT2 * (HD / 256))   // 432 gemm1 blocks
#define G1CV 80                    // wpr-cvt blocks appended: 432+80 = 512 = 2 exact rounds
#define G2WG (NRT1 * (CD / 128))   // 432 gemm2 blocks

typedef __attribute__((ext_vector_type(8))) __bf16 bf16x8;
typedef __attribute__((ext_vector_type(4))) float f32x4;

__device__ __forceinline__ void gl_lds16(const void* g, void* l) {
    __builtin_amdgcn_global_load_lds(
        (const __attribute__((address_space(1))) uint32_t*)g,
        (__attribute__((address_space(3))) uint32_t*)l, 16, 0, 0);
}

__device__ __forceinline__ unsigned bf16bits(float v) {
    __hip_bfloat16 h = __float2bfloat16(v);
    return (unsigned)*reinterpret_cast<unsigned short*>(&h);
}

__device__ __forceinline__ void cvt8(const float* __restrict__ in, __hip_bfloat16* __restrict__ out, int i) {
    float4 a = *(const float4*)(in + i);
    float4 b = *(const float4*)(in + i + 4);
    union { __hip_bfloat16 h[8]; uint4 u; } pk;
    pk.h[0] = __float2bfloat16(a.x); pk.h[1] = __float2bfloat16(a.y);
    pk.h[2] = __float2bfloat16(a.z); pk.h[3] = __float2bfloat16(a.w);
    pk.h[4] = __float2bfloat16(b.x); pk.h[5] = __float2bfloat16(b.y);
    pk.h[6] = __float2bfloat16(b.z); pk.h[7] = __float2bfloat16(b.w);
    *(uint4*)(out + i) = pk.u;
}

// -------- fused front: blocks 0..255 = router(+x cvt); blocks 256+ = wfc cvt + tlist init --------
__global__ __launch_bounds__(256) void k_front(
        const float* __restrict__ x, const float* __restrict__ wr,
        const float* __restrict__ wfc,
        __hip_bfloat16* __restrict__ xb, __hip_bfloat16* __restrict__ wfcb,
        int* __restrict__ eidx, float* __restrict__ pred, int* __restrict__ tlist) {
    if (blockIdx.x >= 256) {
        int ti = (blockIdx.x - 256) * 256 + threadIdx.x;
        if (ti < GCAP) tlist[ti] = -1;
        const int NW = NE * HD * CD;
        const int stride = (gridDim.x - 256) * 256 * 8;
        int i0 = ((blockIdx.x - 256) * 256 + threadIdx.x) * 8;
        for (int i = i0; i < NW; i += stride) cvt8(wfc, wfcb, i);
        return;
    }
    int lane = threadIdx.x & 63;
    int wave = threadIdx.x >> 6;
    float4 wv[NE][3];
    #pragma unroll
    for (int e = 0; e < NE; ++e)
        #pragma unroll
        for (int j = 0; j < 3; ++j)
            wv[e][j] = *(const float4*)(wr + e * CD + j * 256 + lane * 4);
    float sp0 = 0.f, sp1 = 0.f, sp2 = 0.f, sp3 = 0.f, zs = 0.f, hs = 0.f;
    int c0 = 0, c1 = 0, c2 = 0, c3 = 0;
    int t0 = blockIdx.x * 32 + wave * 8;
    for (int it = 0; it < 8; ++it) {
        int t = t0 + it;
        const float* xr = x + (size_t)t * CD;
        float a0 = 0.f, a1 = 0.f, a2 = 0.f, a3 = 0.f;
        #pragma unroll
        for (int j = 0; j < 3; ++j) {
            float4 xv = *(const float4*)(xr + j * 256 + lane * 4);
            a0 += xv.x * wv[0][j].x + xv.y * wv[0][j].y + xv.z * wv[0][j].z + xv.w * wv[0][j].w;
            a1 += xv.x * wv[1][j].x + xv.y * wv[1][j].y + xv.z * wv[1][j].z + xv.w * wv[1][j].w;
            a2 += xv.x * wv[2][j].x + xv.y * wv[2][j].y + xv.z * wv[2][j].z + xv.w * wv[2][j].w;
            a3 += xv.x * wv[3][j].x + xv.y * wv[3][j].y + xv.z * wv[3][j].z + xv.w * wv[3][j].w;
        }
        #pragma unroll
        for (int off = 32; off; off >>= 1) {
            a0 += __shfl_xor(a0, off); a1 += __shfl_xor(a1, off);
            a2 += __shfl_xor(a2, off); a3 += __shfl_xor(a3, off);
        }
        if (lane == 0) {
            float l[NE] = {a0, a1, a2, a3};
            int best = 0; float m = l[0];
            #pragma unroll
            for (int e = 1; e < NE; ++e) if (l[e] > m) { m = l[e]; best = e; }
            float p[NE], s = 0.f;
            #pragma unroll
            for (int e = 0; e < NE; ++e) { p[e] = expf(l[e] - m); s += p[e]; }
            float inv = 1.f / s, ent = 0.f;
            #pragma unroll
            for (int e = 0; e < NE; ++e) {
                p[e] *= inv;
                ent -= p[e] * logf(p[e] + 1e-9f);
            }
            sp0 += p[0]; sp1 += p[1]; sp2 += p[2]; sp3 += p[3];
            float lse = m + logf(s);
            zs += lse * lse; hs += ent;
            if (best == 0) c0++; else if (best == 1) c1++; else if (best == 2) c2++; else c3++;
            eidx[t] = best;
        }
    }
    __shared__ float red[4][10];
    if (lane == 0) {
        red[wave][0] = sp0; red[wave][1] = sp1; red[wave][2] = sp2; red[wave][3] = sp3;
        red[wave][4] = zs;  red[wave][5] = hs;
        red[wave][6] = (float)c0; red[wave][7] = (float)c1;
        red[wave][8] = (float)c2; red[wave][9] = (float)c3;
    }
    __syncthreads();
    if (threadIdx.x < 10)
        pred[blockIdx.x * 10 + threadIdx.x] =
            red[0][threadIdx.x] + red[1][threadIdx.x] + red[2][threadIdx.x] + red[3][threadIdx.x];
    const float* xsrc = x + (size_t)blockIdx.x * 32 * CD;
    __hip_bfloat16* xdst = xb + (size_t)blockIdx.x * 32 * CD;
    #pragma unroll
    for (int c = 0; c < 12; ++c) cvt8(xsrc, xdst, (c * 256 + threadIdx.x) * 8);
}

// -------- deterministic atomic-free scatter (256-row padding); block 0 writes tilee + scalars --------
__global__ __launch_bounds__(256) void k_scatter(
        const int* __restrict__ eidx, const float* __restrict__ pred,
        int* __restrict__ t256, int* __restrict__ t128,
        int* __restrict__ tlist, float* __restrict__ out) {
    const int b = blockIdx.x, tid = threadIdx.x;
    const int lane = tid & 63, wave = tid >> 6;

    float a0 = pred[tid * 10 + 6], a1 = pred[tid * 10 + 7];
    float a2 = pred[tid * 10 + 8], a3 = pred[tid * 10 + 9];
    bool inp = tid < b * 8;
    float p0 = inp ? a0 : 0.f, p1 = inp ? a1 : 0.f, p2 = inp ? a2 : 0.f, p3 = inp ? a3 : 0.f;
    #pragma unroll
    for (int off = 32; off; off >>= 1) {
        a0 += __shfl_xor(a0, off); a1 += __shfl_xor(a1, off);
        a2 += __shfl_xor(a2, off); a3 += __shfl_xor(a3, off);
        p0 += __shfl_xor(p0, off); p1 += __shfl_xor(p1, off);
        p2 += __shfl_xor(p2, off); p3 += __shfl_xor(p3, off);
    }
    __shared__ float redA[4][4], redP[4][4], redS[4][6];
    __shared__ int wcnt[4][4], base_s[4], pfx_s[4], woff_s[4][4];
    if (lane == 0) {
        redA[wave][0] = a0; redA[wave][1] = a1; redA[wave][2] = a2; redA[wave][3] = a3;
        redP[wave][0] = p0; redP[wave][1] = p1; redP[wave][2] = p2; redP[wave][3] = p3;
    }
    int t = b * 256 + tid;
    int e = eidx[t];
    unsigned long long below = (1ull << lane) - 1ull;
    int lrank = 0, mycnt[4];
    #pragma unroll
    for (int ee = 0; ee < NE; ++ee) {
        unsigned long long mm = __ballot(e == ee);
        if (e == ee) lrank = __popcll(mm & below);
        mycnt[ee] = __popcll(mm);
    }
    if (lane == 0) {
        #pragma unroll
        for (int ee = 0; ee < NE; ++ee) wcnt[wave][ee] = mycnt[ee];
    }
    if (b == 0) {
        float s[6];
        #pragma unroll
        for (int c = 0; c < 6; ++c) s[c] = pred[tid * 10 + c];
        #pragma unroll
        for (int off = 32; off; off >>= 1)
            #pragma unroll
            for (int c = 0; c < 6; ++c) s[c] += __shfl_xor(s[c], off);
        if (lane == 0)
            #pragma unroll
            for (int c = 0; c < 6; ++c) redS[wave][c] = s[c];
    }
    __syncthreads();
    if (tid == 0) {
        int cnt[NE], bb = 0, nt = 0;
        #pragma unroll
        for (int ee = 0; ee < NE; ++ee) {
            cnt[ee] = (int)(redA[0][ee] + redA[1][ee] + redA[2][ee] + redA[3][ee] + 0.5f);
            base_s[ee] = bb;
            bb += ((cnt[ee] + 255) >> 8) << 8;
        }
        if (b == 0) {
            for (int ee = 0; ee < NE; ++ee) {
                int tiles = (cnt[ee] + 255) >> 8;
                for (int i = 0; i < tiles; ++i) t256[nt++] = ee;
            }
            for (int i = nt; i < NRT2; ++i) t256[i] = -1;
            for (int i = 0; i < NRT1; ++i) t128[i] = t256[i >> 1];
            float sm[6];
            #pragma unroll
            for (int c = 0; c < 6; ++c)
                sm[c] = redS[0][c] + redS[1][c] + redS[2][c] + redS[3][c];
            float aux = 0.f;
            for (int ee = 0; ee < NE; ++ee)
                aux += (cnt[ee] / (float)NTOK) * (sm[ee] / (float)NTOK);
            out[0] = NE * aux;
            out[1] = sm[4] / (float)NTOK;
            out[2] = (sm[5] / (float)NTOK) / logf((float)NE);
            for (int ee = 0; ee < NE; ++ee) out[3 + ee] = cnt[ee] / (float)NTOK;
        }
    }
    if (tid == 1) {
        #pragma unroll
        for (int ee = 0; ee < NE; ++ee)
            pfx_s[ee] = (int)(redP[0][ee] + redP[1][ee] + redP[2][ee] + redP[3][ee] + 0.5f);
    }
    if (tid == 2) {
        #pragma unroll
        for (int ee = 0; ee < NE; ++ee) {
            int s = 0;
            for (int w = 0; w < 4; ++w) { woff_s[w][ee] = s; s += wcnt[w][ee]; }
        }
    }
    __syncthreads();
    tlist[base_s[e] + pfx_s[e] + woff_s[wave][e] + lrank] = t;
}

// -------- GEMM1: 256x256 tile, BK=64, 8 waves (2Mx4N), 4-phase/K-tile counted-vmcnt,
// single barrier per phase, compiler-managed lgkm waits (ds_reads are compiler-visible) --------
__global__ __launch_bounds__(512, 2) void k_gemm1(
        const __hip_bfloat16* __restrict__ xb, const __hip_bfloat16* __restrict__ wfcb,
        const int* __restrict__ t256, const int* __restrict__ tlist,
        __hip_bfloat16* __restrict__ hbuf,
        const float* __restrict__ wpr, __hip_bfloat16* __restrict__ wprb) {
    __shared__ __align__(16) char lds[131072];   // 2 slots x {A[2kh][256r][64B], B same}
    int bid = (int)blockIdx.x;
    if (bid >= G1WG) {                           // wpr-cvt blocks (round-2 fill)
        const int NW = NE * HD * CD;
        const int stride = G1CV * 512 * 8;
        for (int i = ((bid - G1WG) * 512 + threadIdx.x) * 8; i < NW; i += stride)
            cvt8(wpr, wprb, i);
        return;
    }
    constexpr int Q = G1WG / 8;                  // 54, exact
    int logical = (bid & 7) * Q + (bid >> 3);
    int rt = logical / (HD / 256), ct = logical % (HD / 256);
    const int e = t256[rt];
    if (e < 0) return;

    const int tid = threadIdx.x;
    int r0 = tid >> 2, r1 = 128 + (tid >> 2);
    int ch0 = (tid & 3) ^ ((r0 >> 1) & 3);       // pre-swizzled source chunk (rule #21)
    int ch1 = (tid & 3) ^ ((r1 >> 1) & 3);
    int gt0 = tlist[rt * 256 + r0]; if (gt0 < 0) gt0 = 0;
    int gt1 = tlist[rt * 256 + r1]; if (gt1 < 0) gt1 = 0;
    const __hip_bfloat16* as0 = xb + (size_t)gt0 * CD + ch0 * 8;
    const __hip_bfloat16* as1 = xb + (size_t)gt1 * CD + ch1 * 8;
    const __hip_bfloat16* bs0 = wfcb + ((size_t)e * HD + ct * 256 + r0) * CD + ch0 * 8;
    const __hip_bfloat16* bs1 = wfcb + ((size_t)e * HD + ct * 256 + r1) * CD + ch1 * 8;

    auto stgA = [&](int s, int kh, int kt) {
        char* d = lds + s * 65536 + kh * 16384 + tid * 16;
        gl_lds16(as0 + kt * 64 + kh * 32, d);
        gl_lds16(as1 + kt * 64 + kh * 32, d + 8192);
    };
    auto stgB = [&](int s, int kh, int kt) {
        char* d = lds + s * 65536 + 32768 + kh * 16384 + tid * 16;
        gl_lds16(bs0 + kt * 64 + kh * 32, d);
        gl_lds16(bs1 + kt * 64 + kh * 32, d + 8192);
    };

    const int wv = tid >> 6, lane = tid & 63;
    const int wm = wv >> 2, wn = wv & 3;         // 2M x 4N, per-wave 128x64
    const int lr = lane & 15, lq = lane >> 4;

    auto lda = [&](int s, int kk, int f) -> bf16x8 {
        int r = wm * 128 + f * 16 + lr;
        int off = s * 65536 + kk * 16384 + r * 64 + ((lq ^ ((r >> 1) & 3)) << 4);
        return *(const bf16x8*)(lds + off);
    };
    auto ldb = [&](int s, int kk, int g) -> bf16x8 {
        int r = wn * 64 + g * 16 + lr;
        int off = s * 65536 + 32768 + kk * 16384 + r * 64 + ((lq ^ ((r >> 1) & 3)) << 4);
        return *(const bf16x8*)(lds + off);
    };

    f32x4 acc[8][4];
    #pragma unroll
    for (int f = 0; f < 8; ++f)
        #pragma unroll
        for (int g = 0; g < 4; ++g) acc[f][g] = (f32x4){0.f, 0.f, 0.f, 0.f};

    // single barrier per phase; ds_reads are compiler-visible so lgkm waits are
    // auto-inserted fine-grained (no forced lgkmcnt(0) drain; rule #18 n/a)
    #define PHBAR() do { __builtin_amdgcn_s_barrier(); \
        __builtin_amdgcn_sched_barrier(0); } while (0)
    #define MFMA16(mb) do { __builtin_amdgcn_s_setprio(1); \
        _Pragma("unroll") \
        for (int f = 0; f < 4; ++f) \
            _Pragma("unroll") \
            for (int g = 0; g < 4; ++g) \
                acc[(mb) + f][g] = __builtin_amdgcn_mfma_f32_16x16x32_bf16(afr[f], bfr[g], acc[(mb) + f][g], 0, 0, 0); \
        __builtin_amdgcn_s_setprio(0); } while (0)

    // prologue: kt=0 -> slot0 (issue order fixes vmcnt ledger: Akh0,Bkh0 oldest)
    stgA(0, 0, 0); stgB(0, 0, 0); stgA(0, 1, 0); stgB(0, 1, 0);
    asm volatile("s_waitcnt vmcnt(4)" ::: "memory");   // Akh0+Bkh0 landed
    PHBAR();

    constexpr int NKT = CD / 64;   // 12
    #pragma unroll 2
    for (int kt = 0; kt < NKT; ++kt) {
        const int s = kt & 1, ns = s ^ 1;
        const bool pf = (kt + 1 < NKT);
        bf16x8 afr[4], bfr[4];
        // P0: (kk0, m0-3); stage kt+1 A-kh0
        #pragma unroll
        for (int g = 0; g < 4; ++g) bfr[g] = ldb(s, 0, g);
        #pragma unroll
        for (int f = 0; f < 4; ++f) afr[f] = lda(s, 0, f);
        if (pf) stgA(ns, 0, kt + 1);
        MFMA16(0);
        PHBAR();
        // P1: (kk0, m4-7) B reuse; stage kt+1 B-kh0; vmcnt(4) -> kt's kh1 planes landed
        #pragma unroll
        for (int f = 0; f < 4; ++f) afr[f] = lda(s, 0, 4 + f);
        if (pf) stgB(ns, 0, kt + 1);
        MFMA16(4);
        if (pf) asm volatile("s_waitcnt vmcnt(4)" ::: "memory");
        else    asm volatile("s_waitcnt vmcnt(0)" ::: "memory");
        PHBAR();
        // P2: (kk1, m4-7); stage kt+1 A-kh1
        #pragma unroll
        for (int g = 0; g < 4; ++g) bfr[g] = ldb(s, 1, g);
        #pragma unroll
        for (int f = 0; f < 4; ++f) afr[f] = lda(s, 1, 4 + f);
        if (pf) stgA(ns, 1, kt + 1);
        MFMA16(4);
        PHBAR();
        // P3: (kk1, m0-3) B reuse; stage kt+1 B-kh1; vmcnt(4) -> kt+1's kh0 planes landed
        #pragma unroll
        for (int f = 0; f < 4; ++f) afr[f] = lda(s, 1, f);
        if (pf) stgB(ns, 1, kt + 1);
        MFMA16(0);
        if (pf) asm volatile("s_waitcnt vmcnt(4)" ::: "memory");
        PHBAR();
    }
    #undef PHBAR
    #undef MFMA16

    // epilogue: relu^2 -> bf16 packed stores
    int colb = ct * 256 + wn * 64;
    #pragma unroll
    for (int f = 0; f < 8; ++f) {
        int row0 = rt * 256 + wm * 128 + f * 16 + lq * 4;
        #pragma unroll
        for (int g = 0; g < 4; ++g) {
            #pragma unroll
            for (int q = 0; q < 4; ++q) {
                float v = fmaxf(acc[f][g][q], 0.f);
                v *= v;
                unsigned bb = bf16bits(v);
                unsigned ob = (unsigned)__shfl_xor((int)bb, 1);
                if (!(lane & 1))
                    *(unsigned*)(hbuf + (size_t)(row0 + q) * HD + colb + g * 16 + (lr & 14)) = bb | (ob << 16);
            }
        }
    }
}

// -------- GEMM2 (unchanged best body): 128x128 tile, BK=64, 4 waves, dbuf vmcnt(8) --------
__global__ __launch_bounds__(256, 2) void k_gemm2(
        const __hip_bfloat16* __restrict__ hbuf, const __hip_bfloat16* __restrict__ wprb,
        const int* __restrict__ t128, const int* __restrict__ tlist,
        float* __restrict__ y) {
    __shared__ __align__(16) char lds[65536];
    constexpr int Q = G2WG / 8;          // 54
    int bid = (int)blockIdx.x;
    int logical = (bid & 7) * Q + (bid >> 3);
    constexpr int NCT = CD / 128;
    int rt = logical / NCT, ct = logical % NCT;
    const int e = t128[rt];
    if (e < 0) return;

    const int tid = threadIdx.x;
    const int srow = tid >> 3;
    const int schunk = (tid & 7) ^ (srow & 7);

    const __hip_bfloat16 *ap[4], *bp[4];
    #pragma unroll
    for (int i = 0; i < 4; ++i) {
        int r = i * 32 + srow;
        ap[i] = hbuf + ((size_t)rt * 128 + r) * HD + schunk * 8;
        bp[i] = wprb + ((size_t)e * CD + ct * 128 + r) * HD + schunk * 8;
    }

    auto stage = [&](int bsl, int kt) {
        char* base = lds + bsl * 32768 + tid * 16;
        #pragma unroll
        for (int i = 0; i < 4; ++i) {
            gl_lds16(ap[i] + kt * 64, base + i * 4096);
            gl_lds16(bp[i] + kt * 64, base + 16384 + i * 4096);
        }
    };

    const int wv = tid >> 6, lane = tid & 63;
    const int wm = wv >> 1, wn = wv & 1;
    const int lr = lane & 15, lq = lane >> 4;

    f32x4 acc[4][4];
    #pragma unroll
    for (int m = 0; m < 4; ++m)
        #pragma unroll
        for (int n = 0; n < 4; ++n) acc[m][n] = (f32x4){0.f, 0.f, 0.f, 0.f};

    constexpr int NKT = HD / 64;
    stage(0, 0);
    for (int kt = 0; kt < NKT; ++kt) {
        const int cb = kt & 1;
        if (kt + 1 < NKT) {
            stage(cb ^ 1, kt + 1);
            asm volatile("s_waitcnt vmcnt(8)" ::: "memory");
        } else {
            asm volatile("s_waitcnt vmcnt(0)" ::: "memory");
        }
        __builtin_amdgcn_s_barrier();
        __builtin_amdgcn_sched_barrier(0);
        const char* lA = lds + cb * 32768;
        const char* lB = lA + 16384;
        #pragma unroll
        for (int kh = 0; kh < 2; ++kh) {
            bf16x8 af[4], bq[4];
            #pragma unroll
            for (int m = 0; m < 4; ++m) {
                int r = wm * 64 + m * 16 + lr;
                int c = (kh * 4 + lq) ^ (r & 7);
                af[m] = *(const bf16x8*)(lA + r * 128 + c * 16);
            }
            #pragma unroll
            for (int n = 0; n < 4; ++n) {
                int r = wn * 64 + n * 16 + lr;
                int c = (kh * 4 + lq) ^ (r & 7);
                bq[n] = *(const bf16x8*)(lB + r * 128 + c * 16);
            }
            #pragma unroll
            for (int m = 0; m < 4; ++m)
                #pragma unroll
                for (int n = 0; n < 4; ++n)
                    acc[m][n] = __builtin_amdgcn_mfma_f32_16x16x32_bf16(af[m], bq[n], acc[m][n], 0, 0, 0);
        }
        __builtin_amdgcn_s_barrier();
        __builtin_amdgcn_sched_barrier(0);
    }

    #pragma unroll
    for (int m = 0; m < 4; ++m) {
        #pragma unroll
        for (int q = 0; q < 4; ++q) {
            int grow = rt * 128 + wm * 64 + m * 16 + lq * 4 + q;
            int t = tlist[grow];
            if (t >= 0) {
                float* yp = y + (size_t)t * CD + ct * 128 + wn * 64 + lr;
                #pragma unroll
                for (int n = 0; n < 4; ++n) yp[n * 16] = acc[m][n][q];
            }
        }
    }
}

extern "C" void kernel_launch(void* const* d_in, const int* in_sizes, int n_in,
                              void* d_out, int out_size, void* d_ws, size_t ws_size,
                              hipStream_t stream) {
    const float* x   = (const float*)d_in[0];
    const float* wr  = (const float*)d_in[1];
    const float* wfc = (const float*)d_in[2];
    const float* wpr = (const float*)d_in[3];
    float* y = (float*)d_out;

    char* ws = (char*)d_ws;
    int*   eidx  = (int*)ws;                           // 8192 ints
    int*   t256  = (int*)(ws + 32768);                 // 36 ints
    int*   t128  = (int*)(ws + 32960);                 // 72 ints
    float* pred  = (float*)(ws + 33280);               // 2560 floats -> 43520
    int*   tlist = (int*)(ws + 43776);                 // 9216 ints -> 80640
    __hip_bfloat16* xb   = (__hip_bfloat16*)(ws + 81152);                 // 12.6 MB
    __hip_bfloat16* wfcb = (__hip_bfloat16*)(ws + 81152 + 12582912);      // 18.9 MB
    __hip_bfloat16* wprb = (__hip_bfloat16*)(ws + 81152 + 12582912 + 18874368);
    __hip_bfloat16* hbuf = (__hip_bfloat16*)(ws + 81152 + 12582912 + 2 * 18874368);
    // hbuf 9216*3072*2 = 56.6 MB; total ws use ~107.1 MB

    k_front<<<256 + 1024, 256, 0, stream>>>(x, wr, wfc, xb, wfcb, eidx, pred, tlist);
    k_scatter<<<NTOK / 256, 256, 0, stream>>>(eidx, pred, t256, t128, tlist,
                                              y + (size_t)NTOK * CD);
    k_gemm1<<<G1WG + G1CV, 512, 0, stream>>>(xb, wfcb, t256, tlist, hbuf, wpr, wprb);
    k_gemm2<<<G2WG, 256, 0, stream>>>(hbuf, wprb, t128, tlist, y);
}